// Round 3
// baseline (158.443 us; speedup 1.0000x reference)
//
#include <hip/hip_runtime.h>
#include <hip/hip_bf16.h>

// out[t,z] = sum_i f[t,i] * ( sum_j a[t,j] * C[i,j,z] )
// Stage 1 (MFMA): g = a_bf16 @ C_bf16^T per slab i (A packed ONCE, slab-invariant).
// Stage 2 (VALU): acc += f_fp32[t,i] * g  (f from global/L1, off the LDS pipe).
// Block: Mb=256 (4 Mgroups x Mw=64), Nb=64 (2 Zgroups x Nw=32), 16 i-slabs.
// Grid 256 = 16 mtiles x (zp 2 x kp 8); bid&7 -> XCD so C slices stay in XCD L2.
// K-split partials -> d_ws (no atomics) + reduce kernel; atomic fallback if ws small.

typedef __attribute__((ext_vector_type(8))) short bf16x8;
typedef __attribute__((ext_vector_type(4))) float f32x4;

__device__ __forceinline__ unsigned pkbf16(float x, float y) {
    __hip_bfloat162 h = __float22bfloat162_rn(make_float2(x, y));
    unsigned u; __builtin_memcpy(&u, &h, sizeof(u));
    return u;
}
__device__ __forceinline__ int rot2(int x) { return ((x << 2) & 12) | (x >> 2); }

template<int USE_WS>
__global__ __launch_bounds__(512, 2) void cooc_main(
    const float* __restrict__ fa, const float* __restrict__ Cc,
    float* __restrict__ dst)   // USE_WS: ws partials [kp][4096*128]; else out
{
    // [z 0..63][16 granules of 8 j, rot2-XOR swizzled], row 272 B (17 granules)
    __shared__ __align__(16) ushort bT[2][64 * 136];

    const int bid   = blockIdx.x;
    const int mtile = bid >> 4;
    const int combo = bid & 15;
    const int kp = combo & 7;          // i-chunk (16 slabs)
    const int zp = combo >> 3;         // z-half
    const int t0 = mtile * 256;
    const int i0 = kp * 16;
    const int z0 = zp * 64;

    const int tid  = threadIdx.x;
    const int lane = tid & 63;
    const int wv = tid >> 6;
    const int mg = wv >> 1;            // 0..3 : 64-row group
    const int zg = wv & 1;             // 0..1 : 32-z group
    const int lm = lane & 15;
    const int lk = lane >> 4;

    // ---- pack A (a-part, bf16) ONCE; A-frag row m = lm, k = lk*8+e ----
    union { unsigned u[4]; bf16x8 v; } a_pk[4][4];   // [msub][ks]
    #pragma unroll
    for (int m = 0; m < 4; ++m) {
        const float* ab = fa + (size_t)(t0 + mg * 64 + m * 16 + lm) * 256 + 128;
        #pragma unroll
        for (int ks = 0; ks < 4; ++ks) {
            float4 q0 = *(const float4*)(ab + ks * 32 + lk * 8);
            float4 q1 = *(const float4*)(ab + ks * 32 + lk * 8 + 4);
            a_pk[m][ks].u[0] = pkbf16(q0.x, q0.y);
            a_pk[m][ks].u[1] = pkbf16(q0.z, q0.w);
            a_pk[m][ks].u[2] = pkbf16(q1.x, q1.y);
            a_pk[m][ks].u[3] = pkbf16(q1.z, q1.w);
        }
    }

    // ---- C-slab staging: 4x4 register transpose, bf16 pack, swizzled LDS ----
    const int zq = tid & 15;           // z-quad (64 z)
    const int jq = tid >> 4;           // j-quad 0..31 (128 j)
    const float* csrc = Cc + (size_t)i0 * 16384 + (size_t)(jq * 4) * 128 + z0 + zq * 4;
    union { float4 v4[4]; float f[16]; } La;

    auto loads = [&](int s) {
        const float* p = csrc + (size_t)s * 16384;
        #pragma unroll
        for (int r = 0; r < 4; ++r) La.v4[r] = *(const float4*)(p + r * 128);
    };
    auto writes = [&](int b) {
        #pragma unroll
        for (int rr = 0; rr < 4; ++rr) {
            const int zl = zq * 4 + rr;
            const unsigned lo = pkbf16(La.f[0 * 4 + rr], La.f[1 * 4 + rr]);
            const unsigned hi = pkbf16(La.f[2 * 4 + rr], La.f[3 * 4 + rr]);
            const int P = (jq >> 1) ^ rot2(zl & 15);
            *(uint2*)&bT[b][zl * 136 + P * 8 + (jq & 1) * 4] = make_uint2(lo, hi);
        }
    };

    loads(0); writes(0);
    __syncthreads();

    float acc[4][2][4];                // [msub][nf][reg] fp32
    #pragma unroll
    for (int m = 0; m < 4; ++m)
        #pragma unroll
        for (int n = 0; n < 2; ++n)
            #pragma unroll
            for (int r = 0; r < 4; ++r) acc[m][n][r] = 0.f;

    float4 f4[4][4];                   // f[row(m,r)][i .. i+3], refreshed per 4 slabs

    #pragma unroll 1
    for (int sg = 0; sg < 4; ++sg) {
        #pragma unroll
        for (int m = 0; m < 4; ++m)
            #pragma unroll
            for (int r = 0; r < 4; ++r)
                f4[m][r] = *(const float4*)(fa +
                    (size_t)(t0 + mg * 64 + m * 16 + lk * 4 + r) * 256 + i0 + sg * 4);

        #pragma unroll
        for (int s4 = 0; s4 < 4; ++s4) {
            const int s = sg * 4 + s4;
            const int p = s & 1;
            if (s < 15) loads(s + 1);  // global prefetch for next slab

            bf16x8 Bf[4][2];           // [ks][nf]
            #pragma unroll
            for (int ks = 0; ks < 4; ++ks)
                #pragma unroll
                for (int n = 0; n < 2; ++n) {
                    const int zz = zg * 32 + n * 16 + lm;
                    Bf[ks][n] = *(const bf16x8*)&bT[p][zz * 136 + (((ks * 4 + lk) ^ rot2(lm)) * 8)];
                }

            #pragma unroll
            for (int m = 0; m < 4; ++m)
                #pragma unroll
                for (int n = 0; n < 2; ++n) {
                    f32x4 g = {0.f, 0.f, 0.f, 0.f};
                    #pragma unroll
                    for (int ks = 0; ks < 4; ++ks)
                        g = __builtin_amdgcn_mfma_f32_16x16x32_bf16(a_pk[m][ks].v, Bf[ks][n], g, 0, 0, 0);
                    #pragma unroll
                    for (int r = 0; r < 4; ++r)
                        acc[m][n][r] += ((const float*)&f4[m][r])[s4] * g[r];
                }

            if (s < 15) writes(p ^ 1); // stage next slab into other buffer
            __syncthreads();
        }
    }

    // ---- epilogue: C/D layout col=lm, row=lk*4+r ----
    #pragma unroll
    for (int m = 0; m < 4; ++m)
        #pragma unroll
        for (int n = 0; n < 2; ++n)
            #pragma unroll
            for (int r = 0; r < 4; ++r) {
                const int row = t0 + mg * 64 + m * 16 + lk * 4 + r;
                const int col = z0 + zg * 32 + n * 16 + lm;
                if (USE_WS)
                    dst[(size_t)kp * 524288 + (size_t)row * 128 + col] = acc[m][n][r];
                else
                    atomicAdd(&dst[(size_t)row * 128 + col], acc[m][n][r]);
            }
}

__global__ __launch_bounds__(256) void cooc_reduce(const float* __restrict__ ws,
                                                   float* __restrict__ out) {
    const size_t idx = ((size_t)blockIdx.x * 256 + threadIdx.x) * 4;
    float4 a = *(const float4*)(ws + idx);
    #pragma unroll
    for (int k = 1; k < 8; ++k) {
        float4 b = *(const float4*)(ws + (size_t)k * 524288 + idx);
        a.x += b.x; a.y += b.y; a.z += b.z; a.w += b.w;
    }
    *(float4*)(out + idx) = a;
}

extern "C" void kernel_launch(void* const* d_in, const int* in_sizes, int n_in,
                              void* d_out, int out_size, void* d_ws, size_t ws_size,
                              hipStream_t stream) {
    const float* fa = (const float*)d_in[0];   // (4096, 256): [:,0:128]=f, [:,128:256]=a
    const float* Cc = (const float*)d_in[1];   // (128,128,128)
    float* out = (float*)d_out;                // (4096, 128)

    const bool use_ws = ws_size >= (size_t)8 * 524288 * sizeof(float);   // 16 MiB
    if (use_ws) {
        cooc_main<1><<<256, 512, 0, stream>>>(fa, Cc, (float*)d_ws);
        cooc_reduce<<<512, 256, 0, stream>>>((const float*)d_ws, out);
    } else {
        (void)hipMemsetAsync(out, 0, (size_t)out_size * sizeof(float), stream);
        cooc_main<0><<<256, 512, 0, stream>>>(fa, Cc, out);
    }
}

// Round 4
// 95.470 us; speedup vs baseline: 1.6596x; 1.6596x over previous
//
#include <hip/hip_runtime.h>
#include <hip/hip_bf16.h>

// out[t,z] = sum_i f[t,i] * ( sum_j a[t,j] * C[i,j,z] )
// Stage 1 (MFMA): g = a_bf16 @ C_bf16^T per slab i (A packed ONCE, slab-invariant).
// Stage 2 (VALU): acc += f_fp32[t,i] * g  (f gathered per slab from L1, 16 regs).
// Block 512 thr = 8 waves (4 mg x 2 zg), tile M=256, N=64, 16 i-slabs.
// Grid 256 = 16 mtiles x 2 zp x 8 kp; bid&7=kp -> XCD-affine C slices in XCD L2.
// launch_bounds(512,1): 2nd arg is blocks/CU on this compiler -> 256 VGPR cap
// (R3's (512,2) capped at 128 and spilled ~200 MB to scratch).
// LDS: row pad 272 B (17 granules, odd) + granule rotation (g + row/4)&15:
// b128 reads phase-clean (<=2-way, free), uint2 writes 2-way max.

typedef __attribute__((ext_vector_type(8))) short bf16x8;
typedef __attribute__((ext_vector_type(4))) float f32x4;

__device__ __forceinline__ unsigned pkbf16(float x, float y) {
    __hip_bfloat162 h = __float22bfloat162_rn(make_float2(x, y));
    unsigned u; __builtin_memcpy(&u, &h, sizeof(u));
    return u;
}

template<int USE_WS>
__global__ __launch_bounds__(512, 1) void cooc_main(
    const float* __restrict__ fa, const float* __restrict__ Cc,
    float* __restrict__ dst)   // USE_WS: ws partials [kp][4096*128]; else out
{
    __shared__ __align__(16) ushort bT[2][64 * 136];   // 2 x 64 rows x 272 B

    const int bid   = blockIdx.x;
    const int mtile = bid >> 4;
    const int kp = bid & 7;            // i-chunk (16 slabs) -> XCD id
    const int zp = (bid >> 3) & 1;     // z-half
    const int t0 = mtile * 256;
    const int i0 = kp * 16;
    const int z0 = zp * 64;

    const int tid  = threadIdx.x;
    const int lane = tid & 63;
    const int wv = tid >> 6;
    const int mg = wv >> 1;            // 0..3 : 64-row group
    const int zg = wv & 1;             // 0..1 : 32-z group
    const int lm = lane & 15;
    const int lk = lane >> 4;

    // ---- pack A (a-part, bf16) ONCE; A-frag row m = lm, k = lk*8+e ----
    union { unsigned u[4]; bf16x8 v; } a_pk[4][4];   // [msub][ks] : 64 VGPRs
    #pragma unroll
    for (int m = 0; m < 4; ++m) {
        const float* ab = fa + (size_t)(t0 + mg * 64 + m * 16 + lm) * 256 + 128;
        #pragma unroll
        for (int ks = 0; ks < 4; ++ks) {
            float4 q0 = *(const float4*)(ab + ks * 32 + lk * 8);
            float4 q1 = *(const float4*)(ab + ks * 32 + lk * 8 + 4);
            a_pk[m][ks].u[0] = pkbf16(q0.x, q0.y);
            a_pk[m][ks].u[1] = pkbf16(q0.z, q0.w);
            a_pk[m][ks].u[2] = pkbf16(q1.x, q1.y);
            a_pk[m][ks].u[3] = pkbf16(q1.z, q1.w);
        }
    }

    // ---- C-slab staging: 4x4 register transpose, bf16 pack, swizzled LDS ----
    const int zq = tid & 15;           // z-quad (64 z)
    const int jq = tid >> 4;           // j-quad 0..31 (128 j)
    const float* csrc = Cc + (size_t)i0 * 16384 + (size_t)(jq * 4) * 128 + z0 + zq * 4;
    union { float4 v4[4]; float f[16]; } La;

    auto loads = [&](int s) {
        const float* p = csrc + (size_t)s * 16384;
        #pragma unroll
        for (int r = 0; r < 4; ++r) La.v4[r] = *(const float4*)(p + r * 128);
    };
    auto writes = [&](int b) {
        const int pos = ((jq >> 1) + zq) & 15;       // granule rot by row/4 (=zq)
        #pragma unroll
        for (int rr = 0; rr < 4; ++rr) {
            const int zl = zq * 4 + rr;
            const unsigned lo = pkbf16(La.f[0 * 4 + rr], La.f[1 * 4 + rr]);
            const unsigned hi = pkbf16(La.f[2 * 4 + rr], La.f[3 * 4 + rr]);
            *(uint2*)&bT[b][zl * 136 + pos * 8 + (jq & 1) * 4] = make_uint2(lo, hi);
        }
    };

    loads(0); writes(0);
    __syncthreads();

    float acc[4][2][4];                // [msub][nf][reg] : 32 VGPRs
    #pragma unroll
    for (int m = 0; m < 4; ++m)
        #pragma unroll
        for (int n = 0; n < 2; ++n)
            #pragma unroll
            for (int r = 0; r < 4; ++r) acc[m][n][r] = 0.f;

    // f gather base: rows t0+mg*64+lk*4 + m*16 + r, col i0+s (64 B line / row,
    // L1-resident across all 16 slabs)
    const float* fptr = fa + (size_t)(t0 + mg * 64 + lk * 4) * 256 + i0;

    #pragma unroll 2
    for (int s = 0; s < 16; ++s) {
        const int p = s & 1;

        float fv[4][4];                // 16 VGPRs, gathered first (oldest vmem)
        #pragma unroll
        for (int m = 0; m < 4; ++m)
            #pragma unroll
            for (int r = 0; r < 4; ++r)
                fv[m][r] = fptr[(size_t)(m * 16 + r) * 256 + s];

        if (s < 15) loads(s + 1);      // C prefetch stays in flight past fv use

        bf16x8 Bf[4][2];               // 32 VGPRs
        #pragma unroll
        for (int ks = 0; ks < 4; ++ks)
            #pragma unroll
            for (int n = 0; n < 2; ++n) {
                const int zz = zg * 32 + n * 16 + lm;
                const int pos = ((ks * 4 + lk) + (zz >> 2)) & 15;
                Bf[ks][n] = *(const bf16x8*)&bT[p][zz * 136 + pos * 8];
            }

        #pragma unroll
        for (int m = 0; m < 4; ++m)
            #pragma unroll
            for (int n = 0; n < 2; ++n) {
                f32x4 g = {0.f, 0.f, 0.f, 0.f};
                #pragma unroll
                for (int ks = 0; ks < 4; ++ks)
                    g = __builtin_amdgcn_mfma_f32_16x16x32_bf16(a_pk[m][ks].v, Bf[ks][n], g, 0, 0, 0);
                #pragma unroll
                for (int r = 0; r < 4; ++r)
                    acc[m][n][r] += fv[m][r] * g[r];
            }

        if (s < 15) writes(p ^ 1);     // stage next slab into other buffer
        __syncthreads();
    }

    // ---- epilogue: C/D layout col=lm, row=lk*4+r ----
    #pragma unroll
    for (int m = 0; m < 4; ++m)
        #pragma unroll
        for (int n = 0; n < 2; ++n)
            #pragma unroll
            for (int r = 0; r < 4; ++r) {
                const int row = t0 + mg * 64 + m * 16 + lk * 4 + r;
                const int col = z0 + zg * 32 + n * 16 + lm;
                if (USE_WS)
                    dst[(size_t)kp * 524288 + (size_t)row * 128 + col] = acc[m][n][r];
                else
                    atomicAdd(&dst[(size_t)row * 128 + col], acc[m][n][r]);
            }
}

__global__ __launch_bounds__(256) void cooc_reduce(const float* __restrict__ ws,
                                                   float* __restrict__ out) {
    const size_t idx = ((size_t)blockIdx.x * 256 + threadIdx.x) * 4;
    float4 a = *(const float4*)(ws + idx);
    #pragma unroll
    for (int k = 1; k < 8; ++k) {
        float4 b = *(const float4*)(ws + (size_t)k * 524288 + idx);
        a.x += b.x; a.y += b.y; a.z += b.z; a.w += b.w;
    }
    *(float4*)(out + idx) = a;
}

extern "C" void kernel_launch(void* const* d_in, const int* in_sizes, int n_in,
                              void* d_out, int out_size, void* d_ws, size_t ws_size,
                              hipStream_t stream) {
    const float* fa = (const float*)d_in[0];   // (4096, 256): [:,0:128]=f, [:,128:256]=a
    const float* Cc = (const float*)d_in[1];   // (128,128,128)
    float* out = (float*)d_out;                // (4096, 128)

    const bool use_ws = ws_size >= (size_t)8 * 524288 * sizeof(float);   // 16 MiB
    if (use_ws) {
        cooc_main<1><<<256, 512, 0, stream>>>(fa, Cc, (float*)d_ws);
        cooc_reduce<<<512, 256, 0, stream>>>((const float*)d_ws, out);
    } else {
        (void)hipMemsetAsync(out, 0, (size_t)out_size * sizeof(float), stream);
        cooc_main<0><<<256, 512, 0, stream>>>(fa, Cc, out);
    }
}

// Round 5
// 92.055 us; speedup vs baseline: 1.7212x; 1.0371x over previous
//
#include <hip/hip_runtime.h>
#include <hip/hip_bf16.h>

// out[t,z] = sum_i f[t,i] * ( sum_j a[t,j] * C[i,j,z] )
// Stage 1 (MFMA): g = a_bf16 @ C_slab_bf16^T ; A packed ONCE (slab-invariant).
// Stage 2 (VALU): acc += f[t,i] * g, f read from LDS via broadcast b128.
// Block 256 thr = 4 waves (mg 0..1 x zg 0..1), tile M=128, N=64, 16 i-slabs.
// Grid 512 = 32 mtiles x 2 zp x 8 kp -> 2 blocks/CU (barriers decouple).
// kp = bid&7 -> XCD (R2 FETCH=16MB evidence: bid%8 round-robin holds).
// K-split partials -> d_ws + reduce kernel; atomic fallback if ws small.
// LDS bT: row pad 272 B (17 granules) + granule rot (g + row/4)&15:
// b128 reads and uint2 writes both <=2-way (free per m136).

typedef __attribute__((ext_vector_type(8))) short bf16x8;
typedef __attribute__((ext_vector_type(4))) float f32x4;

__device__ __forceinline__ unsigned pkbf16(float x, float y) {
    __hip_bfloat162 h = __float22bfloat162_rn(make_float2(x, y));
    unsigned u; __builtin_memcpy(&u, &h, sizeof(u));
    return u;
}

template<int USE_WS>
__global__ __launch_bounds__(256, 2) void cooc_main(
    const float* __restrict__ fa, const float* __restrict__ Cc,
    float* __restrict__ dst)   // USE_WS: ws partials [kp][4096*128]; else out
{
    __shared__ __align__(16) ushort bT[2][64 * 136];   // 34.8 KB
    __shared__ float f_lds[16][128];                   // 8 KB, [i_local][row]

    const int bid   = blockIdx.x;
    const int kp    = bid & 7;         // i-chunk -> XCD id
    const int zp    = (bid >> 3) & 1;  // z-half
    const int mtile = bid >> 4;        // 0..31
    const int t0 = mtile * 128;
    const int i0 = kp * 16;
    const int z0 = zp * 64;

    const int tid  = threadIdx.x;      // 0..255
    const int lane = tid & 63;
    const int wv = tid >> 6;           // 0..3
    const int mg = wv >> 1;            // 0..1 : 64-row group
    const int zg = wv & 1;             // 0..1 : 32-z group
    const int lm = lane & 15;
    const int lk = lane >> 4;

    // ---- stage f -> LDS once, transposed to [i][row] ----
    {
        const int row = tid & 127;
        const int sh = (tid >> 7) * 8;     // 0 or 8
        const float* fp = fa + (size_t)(t0 + row) * 256 + i0 + sh;
        float4 v0 = *(const float4*)fp;
        float4 v1 = *(const float4*)(fp + 4);
        f_lds[sh + 0][row] = v0.x; f_lds[sh + 1][row] = v0.y;
        f_lds[sh + 2][row] = v0.z; f_lds[sh + 3][row] = v0.w;
        f_lds[sh + 4][row] = v1.x; f_lds[sh + 5][row] = v1.y;
        f_lds[sh + 6][row] = v1.z; f_lds[sh + 7][row] = v1.w;
    }

    // ---- pack A (a-part, bf16) ONCE; A-frag row m = lm, k = lk*8+e ----
    union { unsigned u[4]; bf16x8 v; } a_pk[4][4];   // 64 VGPRs
    #pragma unroll
    for (int m = 0; m < 4; ++m) {
        const float* ab = fa + (size_t)(t0 + mg * 64 + m * 16 + lm) * 256 + 128;
        #pragma unroll
        for (int ks = 0; ks < 4; ++ks) {
            float4 q0 = *(const float4*)(ab + ks * 32 + lk * 8);
            float4 q1 = *(const float4*)(ab + ks * 32 + lk * 8 + 4);
            a_pk[m][ks].u[0] = pkbf16(q0.x, q0.y);
            a_pk[m][ks].u[1] = pkbf16(q0.z, q0.w);
            a_pk[m][ks].u[2] = pkbf16(q1.x, q1.y);
            a_pk[m][ks].u[3] = pkbf16(q1.z, q1.w);
        }
    }

    // ---- C staging: each thread transposes TWO 4x4 blocks (jq0, jq0+16) ----
    const int zq  = tid & 15;          // z-quad (64 z)
    const int jq0 = tid >> 4;          // 0..15 (+16 for part 1)
    const float* csrc0 = Cc + (size_t)i0 * 16384 + (size_t)(jq0 * 4) * 128 + z0 + zq * 4;
    const float* csrc1 = csrc0 + 16 * 4 * 128;
    union { float4 v4[4]; float f[16]; } La[2];

    auto loads = [&](int s) {
        const float* p0 = csrc0 + (size_t)s * 16384;
        const float* p1 = csrc1 + (size_t)s * 16384;
        #pragma unroll
        for (int r = 0; r < 4; ++r) {
            La[0].v4[r] = *(const float4*)(p0 + r * 128);
            La[1].v4[r] = *(const float4*)(p1 + r * 128);
        }
    };
    auto writes = [&](int b) {
        #pragma unroll
        for (int part = 0; part < 2; ++part) {
            const int jq = jq0 + part * 16;
            const int pos = ((jq >> 1) + zq) & 15;    // granule rot by row/4
            #pragma unroll
            for (int rr = 0; rr < 4; ++rr) {
                const int zl = zq * 4 + rr;
                const unsigned lo = pkbf16(La[part].f[0 * 4 + rr], La[part].f[1 * 4 + rr]);
                const unsigned hi = pkbf16(La[part].f[2 * 4 + rr], La[part].f[3 * 4 + rr]);
                *(uint2*)&bT[b][zl * 136 + pos * 8 + (jq & 1) * 4] = make_uint2(lo, hi);
            }
        }
    };

    loads(0); writes(0);
    __syncthreads();

    float acc[4][2][4];                // 32 VGPRs
    #pragma unroll
    for (int m = 0; m < 4; ++m)
        #pragma unroll
        for (int n = 0; n < 2; ++n)
            #pragma unroll
            for (int r = 0; r < 4; ++r) acc[m][n][r] = 0.f;

    #pragma unroll 2
    for (int s = 0; s < 16; ++s) {
        const int p = s & 1;
        if (s < 15) loads(s + 1);      // global prefetch stays in flight

        // f for this slab: broadcast b128 (rows mg*64+m*16+lk*4 .. +3)
        float4 f4[4];
        #pragma unroll
        for (int m = 0; m < 4; ++m)
            f4[m] = *(const float4*)&f_lds[s][mg * 64 + m * 16 + lk * 4];

        bf16x8 Bf[4][2];               // 32 VGPRs
        #pragma unroll
        for (int ks = 0; ks < 4; ++ks)
            #pragma unroll
            for (int n = 0; n < 2; ++n) {
                const int zz = zg * 32 + n * 16 + lm;
                const int pos = ((ks * 4 + lk) + (zz >> 2)) & 15;
                Bf[ks][n] = *(const bf16x8*)&bT[p][zz * 136 + pos * 8];
            }

        #pragma unroll
        for (int m = 0; m < 4; ++m)
            #pragma unroll
            for (int n = 0; n < 2; ++n) {
                f32x4 g = {0.f, 0.f, 0.f, 0.f};
                #pragma unroll
                for (int ks = 0; ks < 4; ++ks)
                    g = __builtin_amdgcn_mfma_f32_16x16x32_bf16(a_pk[m][ks].v, Bf[ks][n], g, 0, 0, 0);
                acc[m][n][0] += f4[m].x * g[0];
                acc[m][n][1] += f4[m].y * g[1];
                acc[m][n][2] += f4[m].z * g[2];
                acc[m][n][3] += f4[m].w * g[3];
            }

        if (s < 15) writes(p ^ 1);     // stage next slab into other buffer
        __syncthreads();
    }

    // ---- epilogue: C/D layout col=lm, row=lk*4+r ----
    #pragma unroll
    for (int m = 0; m < 4; ++m)
        #pragma unroll
        for (int n = 0; n < 2; ++n)
            #pragma unroll
            for (int r = 0; r < 4; ++r) {
                const int row = t0 + mg * 64 + m * 16 + lk * 4 + r;
                const int col = z0 + zg * 32 + n * 16 + lm;
                if (USE_WS)
                    dst[(size_t)kp * 524288 + (size_t)row * 128 + col] = acc[m][n][r];
                else
                    atomicAdd(&dst[(size_t)row * 128 + col], acc[m][n][r]);
            }
}

__global__ __launch_bounds__(256) void cooc_reduce(const float* __restrict__ ws,
                                                   float* __restrict__ out) {
    const size_t idx = ((size_t)blockIdx.x * 256 + threadIdx.x) * 4;
    float4 a = *(const float4*)(ws + idx);
    #pragma unroll
    for (int k = 1; k < 8; ++k) {
        float4 b = *(const float4*)(ws + (size_t)k * 524288 + idx);
        a.x += b.x; a.y += b.y; a.z += b.z; a.w += b.w;
    }
    *(float4*)(out + idx) = a;
}

extern "C" void kernel_launch(void* const* d_in, const int* in_sizes, int n_in,
                              void* d_out, int out_size, void* d_ws, size_t ws_size,
                              hipStream_t stream) {
    const float* fa = (const float*)d_in[0];   // (4096, 256): [:,0:128]=f, [:,128:256]=a
    const float* Cc = (const float*)d_in[1];   // (128,128,128)
    float* out = (float*)d_out;                // (4096, 128)

    const bool use_ws = ws_size >= (size_t)8 * 524288 * sizeof(float);   // 16 MiB
    if (use_ws) {
        cooc_main<1><<<512, 256, 0, stream>>>(fa, Cc, (float*)d_ws);
        cooc_reduce<<<512, 256, 0, stream>>>((const float*)d_ws, out);
    } else {
        (void)hipMemsetAsync(out, 0, (size_t)out_size * sizeof(float), stream);
        cooc_main<0><<<512, 256, 0, stream>>>(fa, Cc, out);
    }
}